// Round 7
// baseline (36.257 us; speedup 1.0000x reference)
//
#include <hip/hip_runtime.h>

#define K_IN 76      // input feature dim
#define DD 84        // augmented dim
#define HCH 128      // penultimate width
#define CCH 5        // classes

#define LWF 88       // Wf LDS stride (16B-aligned rows; scalar column reads conflict-free)

// ws float offsets
#define OFF_U 0              // U [76][128]
#define OFF_C (K_IN*HCH)     // c [128]

// uacc coef for S_n (n=1..9): 1/n!
__device__ __constant__ float CU[9] = {
    1.f, 0.5f, 1.f/6.f, 1.f/24.f, 1.f/120.f, 1.f/720.f, 1.f/5040.f,
    1.f/40320.f, 1.f/362880.f };
// cacc coef for S_n (n=1..9): 1/(n+1)!
__device__ __constant__ float CC[9] = {
    0.5f, 1.f/6.f, 1.f/24.f, 1.f/120.f, 1.f/720.f, 1.f/5040.f,
    1.f/40320.f, 1.f/362880.f, 1.f/3628800.f };

// ---------------- column-recurrence precompute: 128 independent blocks -----
// Block j computes column j of U and c_j.
//   w_j = Wpen[j][:]  (84-vec);  S_0 = w_j;  S_{n+1} = K*S_n,  K = W^T
//   U[:,j]  = 2*S_0 + sum_{n=1..9} S_n / n!         (rows 0..75 stored)
//   c_j     = bpen[j] + <bode, S_0 + sum_{n=1..9} S_n/(n+1)!>
// Thread i owns element i: S'_i = sum_k K[i][k]*S_k = sum_k W[k][i]*S_k.
__global__ __launch_bounds__(256) void col_kernel(
    const float* __restrict__ W,     // [84][84]
    const float* __restrict__ bode,  // [84]
    const float* __restrict__ Wpen,  // [128][84]
    const float* __restrict__ bpen,  // [128]
    float* __restrict__ ws)
{
    __shared__ float Wf[DD*LWF];     // W row-major, 29.6 KB
    __shared__ float S[88];
    __shared__ float cred[88];

    const int tid = threadIdx.x;
    const int j   = blockIdx.x;      // owned output column
    const bool act = (tid < DD);

    // ---- stage Wf = W (row-major, stride LWF) with all 256 threads ----
    for (int e = tid; e < 1764; e += 256) {
        float4 v = ((const float4*)W)[e];
        int r = e / 21, c4 = (e % 21) * 4;
        *(float4*)&Wf[r*LWF + c4] = v;
    }
    // ---- S0 = Wpen row j ----
    if (tid < DD) S[tid] = Wpen[j*DD + tid];
    if (tid >= DD && tid < 88) cred[tid] = 0.f;   // zero the reduce pad
    __syncthreads();

    // ---- per-thread registers: W column i (conflict-free scalar reads) ----
    float wcol[DD];
    if (act) {
#pragma unroll
        for (int k = 0; k < DD; ++k) wcol[k] = Wf[k*LWF + tid];
    }
    const float breg = act ? bode[tid] : 0.f;
    const float s0   = act ? S[tid]   : 0.f;
    float uacc = 2.f * s0;
    float cacc = s0;

    // ---- 9 Krylov steps ----
#pragma unroll 1
    for (int n = 0; n < 9; ++n) {
        float d = 0.f;
        if (act) {
            float a0 = 0.f, a1 = 0.f, a2 = 0.f, a3 = 0.f;
#pragma unroll
            for (int mg = 0; mg < 21; ++mg) {
                const float4 sv = *(const float4*)&S[mg*4];
                a0 = fmaf(sv.x, wcol[mg*4+0], a0);
                a1 = fmaf(sv.y, wcol[mg*4+1], a1);
                a2 = fmaf(sv.z, wcol[mg*4+2], a2);
                a3 = fmaf(sv.w, wcol[mg*4+3], a3);
            }
            d = (a0 + a1) + (a2 + a3);
        }
        __syncthreads();
        if (act) {
            S[tid] = d;
            uacc = fmaf(CU[n], d, uacc);
            cacc = fmaf(CC[n], d, cacc);
        }
        __syncthreads();
    }

    // ---- outputs ----
    if (tid < K_IN) ws[OFF_U + tid*HCH + j] = uacc;   // U[tid][j]
    if (act) cred[tid] = breg * cacc;
    __syncthreads();
    if (tid == 0) {
        float a0 = 0.f, a1 = 0.f, a2 = 0.f, a3 = 0.f;
#pragma unroll
        for (int mg = 0; mg < 22; ++mg) {
            const float4 v = *(const float4*)&cred[mg*4];
            a0 += v.x; a1 += v.y; a2 += v.z; a3 += v.w;
        }
        ws[OFF_C + j] = bpen[j] + (a0 + a1) + (a2 + a3);
    }
}

// ---------------- main fused kernel (verified round 4, unchanged) ----------
// out[t] = relu(x[t]*U + c) * Wfin^T + bfin
// 512 blocks x 256 thr; block = 128 tokens; thread = 16 tokens x 4 j.
__global__ __launch_bounds__(256) void main_kernel(
    const float* __restrict__ x,     // [65536][76]
    const float* __restrict__ Ug,    // [76][128]
    const float* __restrict__ cg,    // [128]
    const float* __restrict__ Wfin,  // [5][128]
    const float* __restrict__ bfin,  // [5]
    float* __restrict__ out)         // [65536][5]
{
    __shared__ float Ut[K_IN*HCH];   // 38912 B ; reused as final out tile
    __shared__ float xs[128*K_IN];   // 38912 B ; reused as opp[256*21]
    __shared__ float Vl[CCH*HCH];    // 2560 B

    const int tid = threadIdx.x;
    const int tx = tid & 31, ty = tid >> 5;
    const int T0 = blockIdx.x * 128;

    for (int i = tid; i < (K_IN*HCH)/4; i += 256)
        ((float4*)Ut)[i] = ((const float4*)Ug)[i];
    {
        const float4* xg = (const float4*)(x + (size_t)T0 * K_IN);
        for (int i = tid; i < (128*K_IN)/4; i += 256)
            ((float4*)xs)[i] = xg[i];
    }
    for (int i = tid; i < CCH*HCH; i += 256) Vl[i] = Wfin[i];
    __syncthreads();

    const int j0 = tx*4;
    const int tb = ty*16;
    float acc[16][4];
#pragma unroll
    for (int t = 0; t < 16; ++t)
#pragma unroll
        for (int q = 0; q < 4; ++q) acc[t][q] = 0.f;

    for (int kc = 0; kc < 19; ++kc) {
        const float4 u0 = *(const float4*)&Ut[(4*kc+0)*HCH + j0];
        const float4 u1 = *(const float4*)&Ut[(4*kc+1)*HCH + j0];
        const float4 u2 = *(const float4*)&Ut[(4*kc+2)*HCH + j0];
        const float4 u3 = *(const float4*)&Ut[(4*kc+3)*HCH + j0];
#pragma unroll
        for (int ti = 0; ti < 16; ++ti) {
            const float4 xv = *(const float4*)&xs[(tb+ti)*K_IN + 4*kc];
            acc[ti][0] = fmaf(xv.x, u0.x, acc[ti][0]);
            acc[ti][1] = fmaf(xv.x, u0.y, acc[ti][1]);
            acc[ti][2] = fmaf(xv.x, u0.z, acc[ti][2]);
            acc[ti][3] = fmaf(xv.x, u0.w, acc[ti][3]);
            acc[ti][0] = fmaf(xv.y, u1.x, acc[ti][0]);
            acc[ti][1] = fmaf(xv.y, u1.y, acc[ti][1]);
            acc[ti][2] = fmaf(xv.y, u1.z, acc[ti][2]);
            acc[ti][3] = fmaf(xv.y, u1.w, acc[ti][3]);
            acc[ti][0] = fmaf(xv.z, u2.x, acc[ti][0]);
            acc[ti][1] = fmaf(xv.z, u2.y, acc[ti][1]);
            acc[ti][2] = fmaf(xv.z, u2.z, acc[ti][2]);
            acc[ti][3] = fmaf(xv.z, u2.w, acc[ti][3]);
            acc[ti][0] = fmaf(xv.w, u3.x, acc[ti][0]);
            acc[ti][1] = fmaf(xv.w, u3.y, acc[ti][1]);
            acc[ti][2] = fmaf(xv.w, u3.z, acc[ti][2]);
            acc[ti][3] = fmaf(xv.w, u3.w, acc[ti][3]);
        }
    }

    // ---- epilogue: relu, x5 matmul partials, LDS reduce over 32 tx lanes ----
    const float4 cv = *(const float4*)&cg[j0];
    float* opp = xs;                 // [256][21] partials (stride 21, coprime 32)
    float* opf = Ut;                 // [640] final block outputs
    __syncthreads();

    for (int tg = 0; tg < 4; ++tg) {
        float oa[20];
#pragma unroll
        for (int s = 0; s < 4; ++s) {
            const int ti = tg*4 + s;
            const float h0 = fmaxf(acc[ti][0] + cv.x, 0.f);
            const float h1 = fmaxf(acc[ti][1] + cv.y, 0.f);
            const float h2 = fmaxf(acc[ti][2] + cv.z, 0.f);
            const float h3 = fmaxf(acc[ti][3] + cv.w, 0.f);
#pragma unroll
            for (int m = 0; m < CCH; ++m)
                oa[s*5+m] = h0*Vl[m*HCH + j0]     + h1*Vl[m*HCH + j0 + 1]
                          + h2*Vl[m*HCH + j0 + 2] + h3*Vl[m*HCH + j0 + 3];
        }
#pragma unroll
        for (int i = 0; i < 20; ++i) opp[tid*21 + i] = oa[i];
        __syncthreads();
        if (tid < 160) {
            const int typ = tid / 20, rem = tid % 20;   // rem = s*5+m
            float s = 0.f;
            for (int xx = 0; xx < 32; ++xx)
                s += opp[(typ*32 + xx)*21 + rem];
            opf[(typ*16 + tg*4)*5 + rem] = s;
        }
        __syncthreads();
    }

    if (tid < 160) {
        const int gi = tid*4;
        float4 v = *(const float4*)&opf[gi];
        v.x += bfin[(gi+0) % 5]; v.y += bfin[(gi+1) % 5];
        v.z += bfin[(gi+2) % 5]; v.w += bfin[(gi+3) % 5];
        *(float4*)&out[(size_t)T0*CCH + gi] = v;
    }
}

extern "C" void kernel_launch(void* const* d_in, const int* in_sizes, int n_in,
                              void* d_out, int out_size, void* d_ws, size_t ws_size,
                              hipStream_t stream)
{
    (void)in_sizes; (void)n_in; (void)out_size; (void)ws_size;
    const float* x    = (const float*)d_in[0];
    const float* Wode = (const float*)d_in[1];
    const float* bode = (const float*)d_in[2];
    const float* Wpen = (const float*)d_in[3];
    const float* bpen = (const float*)d_in[4];
    const float* Wfin = (const float*)d_in[5];
    const float* bfin = (const float*)d_in[6];
    float* out = (float*)d_out;
    float* wsf = (float*)d_ws;

    col_kernel<<<dim3(HCH), dim3(256), 0, stream>>>(Wode, bode, Wpen, bpen, wsf);
    main_kernel<<<dim3(512), dim3(256), 0, stream>>>(x, wsf + OFF_U, wsf + OFF_C,
                                                     Wfin, bfin, out);
}

// Round 8
// 34.268 us; speedup vs baseline: 1.0580x; 1.0580x over previous
//
#include <hip/hip_runtime.h>

#define K_IN 76      // input feature dim
#define DD 84        // augmented dim
#define HCH 128      // penultimate width
#define CCH 5        // classes

// ws float offsets
#define OFF_U 0              // U [76][128]
#define OFF_C (K_IN*HCH)     // c [128]

// uacc coef for S_n (n=1..9): 1/n!
__device__ __constant__ float CU[9] = {
    1.f, 0.5f, 1.f/6.f, 1.f/24.f, 1.f/120.f, 1.f/720.f, 1.f/5040.f,
    1.f/40320.f, 1.f/362880.f };
// cacc coef for S_n (n=1..9): 1/(n+1)!
__device__ __constant__ float CC[9] = {
    0.5f, 1.f/6.f, 1.f/24.f, 1.f/120.f, 1.f/720.f, 1.f/5040.f,
    1.f/40320.f, 1.f/362880.f, 1.f/3628800.f };

// ---------------- one-wave-per-column precompute: 128 blocks x 64 thr ------
// Block j computes column j of U and c_j; ZERO __syncthreads (wave-sync LDS).
//   S_0 = Wpen[j][:];  S_{n+1} = K*S_n,  K = W^T
//   U[:,j] = 2*S_0 + sum_n S_n/n!   (rows 0..75);  c_j = bpen[j] + <bode, phi>
// Lane l owns elements {l, 64+l} (second valid for l<20).
__global__ __launch_bounds__(64, 1) void col_kernel(
    const float* __restrict__ W,     // [84][84]
    const float* __restrict__ bode,  // [84]
    const float* __restrict__ Wpen,  // [128][84]
    const float* __restrict__ bpen,  // [128]
    float* __restrict__ ws)
{
    __shared__ __align__(16) float Sa[88];
    __shared__ __align__(16) float Sb[88];

    const int l  = threadIdx.x;      // 0..63
    const int j  = blockIdx.x;       // owned output column
    const int i2 = 64 + l;
    const bool has2 = (l < 20);

    // ---- W columns for owned elements into registers (coalesced per k) ----
    float wc1[DD], wc2[DD];
#pragma unroll
    for (int k = 0; k < DD; ++k) wc1[k] = W[k*DD + l];
    if (has2) {
#pragma unroll
        for (int k = 0; k < DD; ++k) wc2[k] = W[k*DD + i2];
    }

    // ---- S0 and per-lane constants ----
    float s1 = Wpen[j*DD + l];
    float s2 = has2 ? Wpen[j*DD + i2] : 0.f;
    const float b1 = bode[l];
    const float b2 = has2 ? bode[i2] : 0.f;

    Sa[l] = s1;
    if (has2) Sa[i2] = s2;
    __threadfence_block();           // wave-local LDS RAW fence (no s_barrier)

    float u1 = 2.f*s1, c1 = s1;
    float u2 = 2.f*s2, c2 = s2;

    // ---- 9 Krylov steps, wave-synchronous double buffer ----
    const float* Sc = Sa;
    float*       Sn = Sb;
#pragma unroll
    for (int n = 0; n < 9; ++n) {
        float a0 = 0.f, a1 = 0.f, a2 = 0.f, a3 = 0.f;
        float e0 = 0.f, e1 = 0.f, e2 = 0.f, e3 = 0.f;
#pragma unroll
        for (int mg = 0; mg < 21; ++mg) {
            const float4 sv = *(const float4*)&Sc[mg*4];   // wave-broadcast
            a0 = fmaf(sv.x, wc1[mg*4+0], a0);
            a1 = fmaf(sv.y, wc1[mg*4+1], a1);
            a2 = fmaf(sv.z, wc1[mg*4+2], a2);
            a3 = fmaf(sv.w, wc1[mg*4+3], a3);
            e0 = fmaf(sv.x, wc2[mg*4+0], e0);
            e1 = fmaf(sv.y, wc2[mg*4+1], e1);
            e2 = fmaf(sv.z, wc2[mg*4+2], e2);
            e3 = fmaf(sv.w, wc2[mg*4+3], e3);
        }
        const float d1 = (a0 + a1) + (a2 + a3);
        const float d2 = (e0 + e1) + (e2 + e3);

        Sn[l] = d1;
        if (has2) Sn[i2] = d2;
        __threadfence_block();

        u1 = fmaf(CU[n], d1, u1);  c1 = fmaf(CC[n], d1, c1);
        u2 = fmaf(CU[n], d2, u2);  c2 = fmaf(CC[n], d2, c2);

        float* t = (float*)Sc; Sc = Sn; Sn = t;
    }

    // ---- store U column ----
    if (l < K_IN)            ws[OFF_U + l*HCH + j]  = u1;
    if (has2 && i2 < K_IN)   ws[OFF_U + i2*HCH + j] = u2;

    // ---- c_j: wave shuffle reduce ----
    float cc = b1*c1 + b2*c2;
#pragma unroll
    for (int off = 32; off > 0; off >>= 1)
        cc += __shfl_down(cc, off, 64);
    if (l == 0) ws[OFF_C + j] = bpen[j] + cc;
}

// ---------------- main fused kernel (verified round 4, unchanged) ----------
// out[t] = relu(x[t]*U + c) * Wfin^T + bfin
// 512 blocks x 256 thr; block = 128 tokens; thread = 16 tokens x 4 j.
__global__ __launch_bounds__(256) void main_kernel(
    const float* __restrict__ x,     // [65536][76]
    const float* __restrict__ Ug,    // [76][128]
    const float* __restrict__ cg,    // [128]
    const float* __restrict__ Wfin,  // [5][128]
    const float* __restrict__ bfin,  // [5]
    float* __restrict__ out)         // [65536][5]
{
    __shared__ float Ut[K_IN*HCH];   // 38912 B ; reused as final out tile
    __shared__ float xs[128*K_IN];   // 38912 B ; reused as opp[256*21]
    __shared__ float Vl[CCH*HCH];    // 2560 B

    const int tid = threadIdx.x;
    const int tx = tid & 31, ty = tid >> 5;
    const int T0 = blockIdx.x * 128;

    for (int i = tid; i < (K_IN*HCH)/4; i += 256)
        ((float4*)Ut)[i] = ((const float4*)Ug)[i];
    {
        const float4* xg = (const float4*)(x + (size_t)T0 * K_IN);
        for (int i = tid; i < (128*K_IN)/4; i += 256)
            ((float4*)xs)[i] = xg[i];
    }
    for (int i = tid; i < CCH*HCH; i += 256) Vl[i] = Wfin[i];
    __syncthreads();

    const int j0 = tx*4;
    const int tb = ty*16;
    float acc[16][4];
#pragma unroll
    for (int t = 0; t < 16; ++t)
#pragma unroll
        for (int q = 0; q < 4; ++q) acc[t][q] = 0.f;

    for (int kc = 0; kc < 19; ++kc) {
        const float4 u0 = *(const float4*)&Ut[(4*kc+0)*HCH + j0];
        const float4 u1 = *(const float4*)&Ut[(4*kc+1)*HCH + j0];
        const float4 u2 = *(const float4*)&Ut[(4*kc+2)*HCH + j0];
        const float4 u3 = *(const float4*)&Ut[(4*kc+3)*HCH + j0];
#pragma unroll
        for (int ti = 0; ti < 16; ++ti) {
            const float4 xv = *(const float4*)&xs[(tb+ti)*K_IN + 4*kc];
            acc[ti][0] = fmaf(xv.x, u0.x, acc[ti][0]);
            acc[ti][1] = fmaf(xv.x, u0.y, acc[ti][1]);
            acc[ti][2] = fmaf(xv.x, u0.z, acc[ti][2]);
            acc[ti][3] = fmaf(xv.x, u0.w, acc[ti][3]);
            acc[ti][0] = fmaf(xv.y, u1.x, acc[ti][0]);
            acc[ti][1] = fmaf(xv.y, u1.y, acc[ti][1]);
            acc[ti][2] = fmaf(xv.y, u1.z, acc[ti][2]);
            acc[ti][3] = fmaf(xv.y, u1.w, acc[ti][3]);
            acc[ti][0] = fmaf(xv.z, u2.x, acc[ti][0]);
            acc[ti][1] = fmaf(xv.z, u2.y, acc[ti][1]);
            acc[ti][2] = fmaf(xv.z, u2.z, acc[ti][2]);
            acc[ti][3] = fmaf(xv.z, u2.w, acc[ti][3]);
            acc[ti][0] = fmaf(xv.w, u3.x, acc[ti][0]);
            acc[ti][1] = fmaf(xv.w, u3.y, acc[ti][1]);
            acc[ti][2] = fmaf(xv.w, u3.z, acc[ti][2]);
            acc[ti][3] = fmaf(xv.w, u3.w, acc[ti][3]);
        }
    }

    // ---- epilogue: relu, x5 matmul partials, LDS reduce over 32 tx lanes ----
    const float4 cv = *(const float4*)&cg[j0];
    float* opp = xs;                 // [256][21] partials (stride 21, coprime 32)
    float* opf = Ut;                 // [640] final block outputs
    __syncthreads();

    for (int tg = 0; tg < 4; ++tg) {
        float oa[20];
#pragma unroll
        for (int s = 0; s < 4; ++s) {
            const int ti = tg*4 + s;
            const float h0 = fmaxf(acc[ti][0] + cv.x, 0.f);
            const float h1 = fmaxf(acc[ti][1] + cv.y, 0.f);
            const float h2 = fmaxf(acc[ti][2] + cv.z, 0.f);
            const float h3 = fmaxf(acc[ti][3] + cv.w, 0.f);
#pragma unroll
            for (int m = 0; m < CCH; ++m)
                oa[s*5+m] = h0*Vl[m*HCH + j0]     + h1*Vl[m*HCH + j0 + 1]
                          + h2*Vl[m*HCH + j0 + 2] + h3*Vl[m*HCH + j0 + 3];
        }
#pragma unroll
        for (int i = 0; i < 20; ++i) opp[tid*21 + i] = oa[i];
        __syncthreads();
        if (tid < 160) {
            const int typ = tid / 20, rem = tid % 20;   // rem = s*5+m
            float s = 0.f;
            for (int xx = 0; xx < 32; ++xx)
                s += opp[(typ*32 + xx)*21 + rem];
            opf[(typ*16 + tg*4)*5 + rem] = s;
        }
        __syncthreads();
    }

    if (tid < 160) {
        const int gi = tid*4;
        float4 v = *(const float4*)&opf[gi];
        v.x += bfin[(gi+0) % 5]; v.y += bfin[(gi+1) % 5];
        v.z += bfin[(gi+2) % 5]; v.w += bfin[(gi+3) % 5];
        *(float4*)&out[(size_t)T0*CCH + gi] = v;
    }
}

extern "C" void kernel_launch(void* const* d_in, const int* in_sizes, int n_in,
                              void* d_out, int out_size, void* d_ws, size_t ws_size,
                              hipStream_t stream)
{
    (void)in_sizes; (void)n_in; (void)out_size; (void)ws_size;
    const float* x    = (const float*)d_in[0];
    const float* Wode = (const float*)d_in[1];
    const float* bode = (const float*)d_in[2];
    const float* Wpen = (const float*)d_in[3];
    const float* bpen = (const float*)d_in[4];
    const float* Wfin = (const float*)d_in[5];
    const float* bfin = (const float*)d_in[6];
    float* out = (float*)d_out;
    float* wsf = (float*)d_ws;

    col_kernel<<<dim3(HCH), dim3(64), 0, stream>>>(Wode, bode, Wpen, bpen, wsf);
    main_kernel<<<dim3(512), dim3(256), 0, stream>>>(x, wsf + OFF_U, wsf + OFF_C,
                                                     Wfin, bfin, out);
}